// Round 3
// baseline (736.870 us; speedup 1.0000x reference)
//
#include <hip/hip_runtime.h>
#include <hip/hip_bf16.h>

#define NB 60000
#define NP 2000
#define NC 4000
#define EM_N 150000
#define EP_N 300000
#define EI_N 150000

typedef __hip_bfloat16 bf16;

__device__ __forceinline__ float toF(float x) { return x; }
__device__ __forceinline__ float toF(bf16 x) { return __bfloat162float(x); }
__device__ __forceinline__ void stC(float* C, size_t idx, float v) { C[idx] = v; }
__device__ __forceinline__ void stC(bf16* C, size_t idx, float v) { C[idx] = __float2bfloat16(v); }

// ---------------- GEMM: C[M,128] = A[M,128] @ W[128,128] (+bias) (+=C) ----------------
// W is fp32, read from global (64KB, L2-resident, shared by all blocks).
template<typename AT, typename CT, bool ACC, bool BIAS>
__global__ void gemm128_kernel(const AT* __restrict__ A, const float* __restrict__ W,
                               const float* __restrict__ bias, CT* __restrict__ C, int M) {
    __shared__ float Al[16 * 128];
    const int tid = threadIdx.x;
    const int row0 = blockIdx.x * 16;
    for (int i = tid; i < 16 * 128; i += 256) {
        int r = row0 + (i >> 7);
        float v = 0.f;
        if (r < M) v = toF(A[(size_t)r * 128 + (i & 127)]);
        Al[i] = v;
    }
    __syncthreads();

    const int col = tid & 127;
    const int rg = tid >> 7;  // 0/1 -> 8 rows each
    float acc[8];
#pragma unroll
    for (int i = 0; i < 8; i++) acc[i] = 0.f;
    for (int k = 0; k < 128; k++) {
        float w = W[k * 128 + col];
#pragma unroll
        for (int i = 0; i < 8; i++) acc[i] += Al[(rg * 8 + i) * 128 + k] * w;
    }
    float bv = 0.f;
    if constexpr (BIAS) bv = bias[col];
#pragma unroll
    for (int i = 0; i < 8; i++) {
        int r = row0 + rg * 8 + i;
        if (r < M) {
            size_t idx = (size_t)r * 128 + col;
            float o = acc[i] + bv;
            if constexpr (ACC) o += toF(C[idx]);
            stC(C, idx, o);
        }
    }
}

// ---------------- GATv2 logits: per (edge, head) ----------------
__global__ void gat_logits_kernel(const bf16* __restrict__ xl, const bf16* __restrict__ xr,
                                  const int* __restrict__ em, const float* __restrict__ att,
                                  float* __restrict__ elog, float* __restrict__ sums) {
    int t = blockIdx.x * 256 + threadIdx.x;
    if (t >= EM_N * 4) return;
    int e = t >> 2, h = t & 3;
    int s = em[e], d = em[EM_N + e];
    const bf16* pl = xl + (size_t)s * 128 + h * 32;
    const bf16* pr = xr + (size_t)d * 128 + h * 32;
    float acc = 0.f;
#pragma unroll
    for (int j = 0; j < 32; j++) {
        float u = toF(pl[j]) + toF(pr[j]);
        u = u > 0.f ? u : 0.2f * u;
        acc += u * att[h * 32 + j];
    }
    float p = __expf(acc);
    elog[t] = p;
    atomicAdd(&sums[d * 4 + h], p);
}

// ---------------- GATv2 aggregation: per (edge, elem) ----------------
__global__ void gat_agg_kernel(const bf16* __restrict__ xl, const int* __restrict__ em,
                               const float* __restrict__ elog, const float* __restrict__ sums,
                               float* __restrict__ acc) {
    int t = blockIdx.x * 256 + threadIdx.x;
    if (t >= EM_N * 128) return;
    int e = t >> 7, i = t & 127, h = i >> 5;
    int s = em[e], d = em[EM_N + e];
    float alpha = elog[e * 4 + h] / (sums[d * 4 + h] + 1e-16f);
    atomicAdd(&acc[(size_t)d * 128 + i], toF(xl[(size_t)s * 128 + i]) * alpha);
}

// ---------------- TransformerConv logits: per (edge, head) ----------------
__global__ void tr_logits_kernel(const bf16* __restrict__ q, const bf16* __restrict__ k,
                                 const int* __restrict__ ep, const float* __restrict__ ea_p,
                                 const float* __restrict__ We,
                                 float* __restrict__ elog, float* __restrict__ sums) {
    int t = blockIdx.x * 256 + threadIdx.x;
    if (t >= EP_N * 4) return;
    int e = t >> 2, h = t & 3;
    int s = ep[e], d = ep[EP_N + e];
    float ea = ea_p[e];
    const bf16* pq = q + (size_t)d * 128 + h * 32;
    const bf16* pk = k + (size_t)s * 128 + h * 32;
    float acc = 0.f;
#pragma unroll
    for (int j = 0; j < 32; j++) {
        acc += toF(pq[j]) * (toF(pk[j]) + ea * We[h * 32 + j]);
    }
    float p = __expf(acc * 0.17677669529663687f);  // 1/sqrt(32)
    elog[t] = p;
    atomicAdd(&sums[d * 4 + h], p);
}

// ---------------- TransformerConv aggregation: per (edge, elem) ----------------
__global__ void tr_agg_kernel(const bf16* __restrict__ v, const int* __restrict__ ep,
                              const float* __restrict__ ea_p, const float* __restrict__ We,
                              const float* __restrict__ elog, const float* __restrict__ sums,
                              float* __restrict__ acc) {
    int t = blockIdx.x * 256 + threadIdx.x;
    if (t >= EP_N * 128) return;
    int e = t >> 7, i = t & 127, h = i >> 5;
    int s = ep[e], d = ep[EP_N + e];
    float ea = ea_p[e];
    float alpha = elog[e * 4 + h] / (sums[d * 4 + h] + 1e-16f);
    atomicAdd(&acc[(size_t)d * 128 + i], (toF(v[(size_t)s * 128 + i]) + ea * We[i]) * alpha);
}

// ---------------- SAGE scatter: per (edge, elem) ----------------
__global__ void sage_agg_kernel(const float* __restrict__ xb, const int* __restrict__ ei,
                                float* __restrict__ summ, float* __restrict__ cnt) {
    int t = blockIdx.x * 256 + threadIdx.x;
    if (t >= EI_N * 128) return;
    int e = t >> 7, i = t & 127;
    int s = ei[e], d = ei[EI_N + e];
    atomicAdd(&summ[(size_t)d * 128 + i], xb[(size_t)s * 128 + i]);
    if (i == 0) atomicAdd(&cnt[d], 1.0f);
}

// ---------------- SAGE mean (in-place) ----------------
__global__ void sage_mean_kernel(float* __restrict__ summ, const float* __restrict__ cnt) {
    int t = blockIdx.x * 256 + threadIdx.x;
    if (t >= NC * 128) return;
    int c = t >> 7;
    summ[t] /= fmaxf(cnt[c], 1.0f);
}

// ---------------- LayerNorm ball: in = acc(skip+gat+tr) + x + g_b ----------------
__global__ void ln_ball_kernel(const float* __restrict__ acc,
                               const float* __restrict__ x, const float* __restrict__ gb,
                               const float* __restrict__ g, const float* __restrict__ b,
                               float* __restrict__ out) {
    int gid = blockIdx.x * 256 + threadIdx.x;
    int row = gid >> 6, lane = gid & 63;
    if (row >= NB) return;
    size_t i0 = (size_t)row * 128 + lane, i1 = i0 + 64;
    float v0 = acc[i0] + x[i0] + gb[lane];
    float v1 = acc[i1] + x[i1] + gb[lane + 64];
    float s = v0 + v1;
#pragma unroll
    for (int off = 32; off; off >>= 1) s += __shfl_down(s, off);
    float mu = __shfl(s, 0) * (1.f / 128.f);
    float d0 = v0 - mu, d1 = v1 - mu;
    float qv = d0 * d0 + d1 * d1;
#pragma unroll
    for (int off = 32; off; off >>= 1) qv += __shfl_down(qv, off);
    float inv = rsqrtf(__shfl(qv, 0) * (1.f / 128.f) + 1e-5f);
    out[i0] = d0 * inv * g[lane] + b[lane];
    out[i1] = d1 * inv * g[lane + 64] + b[lane + 64];
}

// ---------------- LayerNorm ctx: in = ctxbuf + x ----------------
__global__ void ln_ctx_kernel(const float* __restrict__ cb, const float* __restrict__ x,
                              const float* __restrict__ g, const float* __restrict__ b,
                              float* __restrict__ out) {
    int gid = blockIdx.x * 256 + threadIdx.x;
    int row = gid >> 6, lane = gid & 63;
    if (row >= NC) return;
    size_t i0 = (size_t)row * 128 + lane, i1 = i0 + 64;
    float v0 = cb[i0] + x[i0];
    float v1 = cb[i1] + x[i1];
    float s = v0 + v1;
#pragma unroll
    for (int off = 32; off; off >>= 1) s += __shfl_down(s, off);
    float mu = __shfl(s, 0) * (1.f / 128.f);
    float d0 = v0 - mu, d1 = v1 - mu;
    float qv = d0 * d0 + d1 * d1;
#pragma unroll
    for (int off = 32; off; off >>= 1) qv += __shfl_down(qv, off);
    float inv = rsqrtf(__shfl(qv, 0) * (1.f / 128.f) + 1e-5f);
    out[i0] = d0 * inv * g[lane] + b[lane];
    out[i1] = d1 * inv * g[lane + 64] + b[lane + 64];
}

// ---------------- player passthrough ----------------
__global__ void copy_player_kernel(const float* __restrict__ xp, float* __restrict__ out) {
    int t = blockIdx.x * 256 + threadIdx.x;
    if (t >= NP * 128) return;
    out[t] = xp[t];
}

extern "C" void kernel_launch(void* const* d_in, const int* in_sizes, int n_in,
                              void* d_out, int out_size, void* d_ws, size_t ws_size,
                              hipStream_t stream) {
    const float* x_ball = (const float*)d_in[0];
    const float* x_player = (const float*)d_in[1];
    const float* x_context = (const float*)d_in[2];
    const int* em = (const int*)d_in[3];
    const int* ep = (const int*)d_in[4];
    const int* ei = (const int*)d_in[5];
    const float* ea_p = (const float*)d_in[6];
    const float* g_Wl = (const float*)d_in[7];
    const float* g_Wr = (const float*)d_in[8];
    const float* g_att = (const float*)d_in[9];
    const float* g_b = (const float*)d_in[10];
    const float* t_Wq = (const float*)d_in[11];
    const float* t_bq = (const float*)d_in[12];
    const float* t_Wk = (const float*)d_in[13];
    const float* t_bk = (const float*)d_in[14];
    const float* t_Wv = (const float*)d_in[15];
    const float* t_bv = (const float*)d_in[16];
    const float* t_We = (const float*)d_in[17];
    const float* t_Wskip = (const float*)d_in[18];
    const float* t_bskip = (const float*)d_in[19];
    const float* s_Wl = (const float*)d_in[20];
    const float* s_bl = (const float*)d_in[21];
    const float* s_Wr = (const float*)d_in[22];
    const float* ln_ball_g = (const float*)d_in[23];
    const float* ln_ball_b = (const float*)d_in[24];
    const float* ln_ctx_g = (const float*)d_in[25];
    const float* ln_ctx_b = (const float*)d_in[26];
    float* out = (float*)d_out;

    // ---- workspace layout: ~76 MB total ----
    float* ws = (float*)d_ws;
    size_t o = 0;
    float* ball_acc = ws + o; o += (size_t)NB * 128;   // skip gemm init, then atomics
    float* elog_m = ws + o;   o += (size_t)EM_N * 4;
    float* elog_p = ws + o;   o += (size_t)EP_N * 4;
    float* ctxb = ws + o;     o += (size_t)NC * 128;
    // contiguous zero-init block (atomic targets not pre-written by a gemm)
    float* zero_base = ws + o;
    float* sum_m = ws + o;    o += (size_t)NB * 4;
    float* sum_p = ws + o;    o += (size_t)NB * 4;
    float* summ = ws + o;     o += (size_t)NC * 128;
    float* cnt = ws + o;      o += (size_t)NC;
    size_t zero_bytes = (size_t)(ws + o - zero_base) * sizeof(float);
    // bf16 region (read-only intermediates)
    bf16* bws = (bf16*)(ws + o);
    size_t ob = 0;
    bf16* xl = bws + ob;      ob += (size_t)NP * 128;
    bf16* bufA = bws + ob;    ob += (size_t)NB * 128;  // xr, then q
    bf16* bufB = bws + ob;    ob += (size_t)NB * 128;  // k, then v

    hipMemsetAsync(zero_base, 0, zero_bytes, stream);

    dim3 blk(256);
    // ---- GAT inputs + skip init ----
    gemm128_kernel<float, bf16, false, false><<<(NP + 15) / 16, blk, 0, stream>>>(x_player, g_Wl, nullptr, xl, NP);
    gemm128_kernel<float, bf16, false, false><<<(NB + 15) / 16, blk, 0, stream>>>(x_ball, g_Wr, nullptr, bufA, NB);
    gemm128_kernel<float, float, false, true><<<(NB + 15) / 16, blk, 0, stream>>>(x_ball, t_Wskip, t_bskip, ball_acc, NB);

    // ---- GATv2 ----
    gat_logits_kernel<<<(EM_N * 4 + 255) / 256, blk, 0, stream>>>(xl, bufA, em, g_att, elog_m, sum_m);
    gat_agg_kernel<<<(EM_N * 128 + 255) / 256, blk, 0, stream>>>(xl, em, elog_m, sum_m, ball_acc);

    // ---- TransformerConv (bufA reused for q, bufB for k then v) ----
    gemm128_kernel<float, bf16, false, true><<<(NB + 15) / 16, blk, 0, stream>>>(x_ball, t_Wq, t_bq, bufA, NB);
    gemm128_kernel<float, bf16, false, true><<<(NB + 15) / 16, blk, 0, stream>>>(x_ball, t_Wk, t_bk, bufB, NB);
    tr_logits_kernel<<<(EP_N * 4 + 255) / 256, blk, 0, stream>>>(bufA, bufB, ep, ea_p, t_We, elog_p, sum_p);
    gemm128_kernel<float, bf16, false, true><<<(NB + 15) / 16, blk, 0, stream>>>(x_ball, t_Wv, t_bv, bufB, NB);
    tr_agg_kernel<<<(EP_N * 128 + 255) / 256, blk, 0, stream>>>(bufB, ep, ea_p, t_We, elog_p, sum_p, ball_acc);

    // ---- SAGE ----
    gemm128_kernel<float, float, false, false><<<(NC + 15) / 16, blk, 0, stream>>>(x_context, s_Wr, nullptr, ctxb, NC);
    sage_agg_kernel<<<(EI_N * 128 + 255) / 256, blk, 0, stream>>>(x_ball, ei, summ, cnt);
    sage_mean_kernel<<<(NC * 128 + 255) / 256, blk, 0, stream>>>(summ, cnt);
    gemm128_kernel<float, float, true, true><<<(NC + 15) / 16, blk, 0, stream>>>(summ, s_Wl, s_bl, ctxb, NC);

    // ---- epilogues ----
    ln_ball_kernel<<<(NB * 64 + 255) / 256, blk, 0, stream>>>(ball_acc, x_ball, g_b, ln_ball_g, ln_ball_b, out);
    ln_ctx_kernel<<<(NC * 64 + 255) / 256, blk, 0, stream>>>(ctxb, x_context, ln_ctx_g, ln_ctx_b,
                                                             out + (size_t)NB * 128);
    copy_player_kernel<<<(NP * 128 + 255) / 256, blk, 0, stream>>>(x_player,
                                                                   out + (size_t)(NB + NC) * 128);
}

// Round 4
// 550.193 us; speedup vs baseline: 1.3393x; 1.3393x over previous
//
#include <hip/hip_runtime.h>
#include <hip/hip_bf16.h>

#define NB 60000
#define NP 2000
#define NC 4000
#define EM_N 150000
#define EP_N 300000
#define EI_N 150000
#define SEG_TOT (NB + NB + NC)                        // 124000 segment counters
#define SCAN_BLK 1024
#define NPART ((SEG_TOT + SCAN_BLK - 1) / SCAN_BLK)   // 122

typedef __hip_bfloat16 bf16;

__device__ __forceinline__ float toF(float x) { return x; }
__device__ __forceinline__ float toF(bf16 x) { return __bfloat162float(x); }
__device__ __forceinline__ void stC(float* C, size_t idx, float v) { C[idx] = v; }
__device__ __forceinline__ void stC(bf16* C, size_t idx, float v) { C[idx] = __float2bfloat16(v); }

// ---------------- generic GEMM: C[M,128] = A[M,128] @ W[128,128] (+bias) (+=C) ----------------
template<typename AT, typename CT, bool ACC, bool BIAS>
__global__ void gemm128_kernel(const AT* __restrict__ A, const float* __restrict__ W,
                               const float* __restrict__ bias, CT* __restrict__ C, int M) {
    __shared__ float Al[16 * 128];
    const int tid = threadIdx.x;
    const int row0 = blockIdx.x * 16;
    for (int i = tid; i < 16 * 128; i += 256) {
        int r = row0 + (i >> 7);
        Al[i] = (r < M) ? toF(A[(size_t)r * 128 + (i & 127)]) : 0.f;
    }
    __syncthreads();
    const int col = tid & 127, rg = tid >> 7;
    float acc[8];
#pragma unroll
    for (int i = 0; i < 8; i++) acc[i] = 0.f;
    for (int k = 0; k < 128; k++) {
        float w = W[k * 128 + col];
#pragma unroll
        for (int i = 0; i < 8; i++) acc[i] += Al[(rg * 8 + i) * 128 + k] * w;
    }
    float bv = 0.f;
    if constexpr (BIAS) bv = bias[col];
#pragma unroll
    for (int i = 0; i < 8; i++) {
        int r = row0 + rg * 8 + i;
        if (r < M) {
            size_t idx = (size_t)r * 128 + col;
            float o = acc[i] + bv;
            if constexpr (ACC) o += toF(C[idx]);
            stC(C, idx, o);
        }
    }
}

// ---------------- fused 5-output GEMM on x_ball: xr, q, k, v, skip (all bf16) ----------------
__global__ void gemm128x5_kernel(const float* __restrict__ A,
    const float* __restrict__ W0, const float* __restrict__ W1, const float* __restrict__ W2,
    const float* __restrict__ W3, const float* __restrict__ W4,
    const float* __restrict__ b1, const float* __restrict__ b2, const float* __restrict__ b3,
    const float* __restrict__ b4,
    bf16* __restrict__ O0, bf16* __restrict__ O1, bf16* __restrict__ O2,
    bf16* __restrict__ O3, bf16* __restrict__ O4, int M) {
    __shared__ float Al[16 * 128];
    const int tid = threadIdx.x;
    const int row0 = blockIdx.x * 16;
    for (int i = tid; i < 16 * 128; i += 256) {
        int r = row0 + (i >> 7);
        Al[i] = (r < M) ? A[(size_t)r * 128 + (i & 127)] : 0.f;
    }
    __syncthreads();
    const int col = tid & 127, rg = tid >> 7;
    float a0[8] = {0}, a1[8] = {0}, a2[8] = {0}, a3[8] = {0}, a4[8] = {0};
    for (int k = 0; k < 128; k++) {
        float w0 = W0[k * 128 + col], w1 = W1[k * 128 + col], w2 = W2[k * 128 + col];
        float w3 = W3[k * 128 + col], w4 = W4[k * 128 + col];
#pragma unroll
        for (int i = 0; i < 8; i++) {
            float a = Al[(rg * 8 + i) * 128 + k];  // LDS broadcast (same addr all lanes) - free
            a0[i] += a * w0; a1[i] += a * w1; a2[i] += a * w2; a3[i] += a * w3; a4[i] += a * w4;
        }
    }
    float bv1 = b1[col], bv2 = b2[col], bv3 = b3[col], bv4 = b4[col];
#pragma unroll
    for (int i = 0; i < 8; i++) {
        int r = row0 + rg * 8 + i;
        if (r < M) {
            size_t idx = (size_t)r * 128 + col;
            O0[idx] = __float2bfloat16(a0[i]);
            O1[idx] = __float2bfloat16(a1[i] + bv1);
            O2[idx] = __float2bfloat16(a2[i] + bv2);
            O3[idx] = __float2bfloat16(a3[i] + bv3);
            O4[idx] = __float2bfloat16(a4[i] + bv4);
        }
    }
}

// ---------------- CSR build ----------------
__global__ void hist_kernel(const int* __restrict__ dst, int n, int segBase, int* __restrict__ counts) {
    int t = blockIdx.x * 256 + threadIdx.x;
    if (t >= n) return;
    atomicAdd(&counts[segBase + dst[t]], 1);
}

__global__ void scan1_kernel(const int* __restrict__ counts, int* __restrict__ offsets,
                             int* __restrict__ partials) {
    __shared__ int sd[256];
    int b = blockIdx.x, tid = threadIdx.x;
    int base = b * SCAN_BLK + tid * 4;
    int v[4]; int ts = 0;
#pragma unroll
    for (int j = 0; j < 4; j++) { int idx = base + j; v[j] = (idx < SEG_TOT) ? counts[idx] : 0; ts += v[j]; }
    sd[tid] = ts;
    for (int off = 1; off < 256; off <<= 1) {
        __syncthreads(); int t = (tid >= off) ? sd[tid - off] : 0;
        __syncthreads(); sd[tid] += t;
    }
    int run = sd[tid] - ts;  // exclusive base within block
#pragma unroll
    for (int j = 0; j < 4; j++) { int idx = base + j; if (idx < SEG_TOT) offsets[idx] = run; run += v[j]; }
    if (tid == 255) partials[b] = sd[255];
}

__global__ void scan2_kernel(int* __restrict__ partials) {
    __shared__ int sd[256];
    int tid = threadIdx.x;
    int v = (tid < NPART) ? partials[tid] : 0;
    sd[tid] = v;
    for (int off = 1; off < 256; off <<= 1) {
        __syncthreads(); int t = (tid >= off) ? sd[tid - off] : 0;
        __syncthreads(); sd[tid] += t;
    }
    if (tid < NPART) partials[tid] = sd[tid] - v;  // exclusive
}

__global__ void scan3_kernel(int* __restrict__ offsets, const int* __restrict__ partials,
                             int* __restrict__ cursors) {
    int t = blockIdx.x * 256 + threadIdx.x;
    if (t >= SEG_TOT) return;
    int o = offsets[t] + partials[t >> 10];
    offsets[t] = o;
    cursors[t] = o;
}

__global__ void fill_kernel(const int* __restrict__ dst, int n, int segBase,
                            int* __restrict__ cursors, int* __restrict__ pool) {
    int t = blockIdx.x * 256 + threadIdx.x;
    if (t >= n) return;
    int pos = atomicAdd(&cursors[segBase + dst[t]], 1);
    pool[pos] = t;
}

// ---------------- fused ball kernel: GAT + TR (logits+softmax+agg) + skip + residual + LN ----------------
// one wave per ball node; lane l owns elements l and l+64; heads via 32-lane shfl_xor reductions
__global__ void ball_fused_kernel(
    const bf16* __restrict__ xl, const bf16* __restrict__ xr, const bf16* __restrict__ q,
    const bf16* __restrict__ k, const bf16* __restrict__ v, const bf16* __restrict__ skip,
    const float* __restrict__ x_ball, const float* __restrict__ g_att, const float* __restrict__ g_b,
    const float* __restrict__ ea_p, const float* __restrict__ We,
    const int* __restrict__ em, const int* __restrict__ ep,
    const int* __restrict__ offsets, const int* __restrict__ counts, const int* __restrict__ pool,
    const float* __restrict__ ln_g, const float* __restrict__ ln_b, float* __restrict__ out) {
    int gid = blockIdx.x * 256 + threadIdx.x;
    int d = gid >> 6, l = gid & 63;
    if (d >= NB) return;
    int i0 = l, i1 = l + 64;
    size_t rowD = (size_t)d * 128;

    // ---- GATv2 (player->ball) ----
    float xr0 = toF(xr[rowD + i0]), xr1 = toF(xr[rowD + i1]);
    float at0 = g_att[i0], at1 = g_att[i1];
    float num0 = 0.f, num1 = 0.f, den0 = 0.f, den1 = 0.f;
    int beg = offsets[d], cnt = counts[d];
    for (int j = 0; j < cnt; j++) {
        int e = pool[beg + j];
        int s = em[e];
        size_t rs = (size_t)s * 128;
        float x0 = toF(xl[rs + i0]), x1 = toF(xl[rs + i1]);
        float u0 = x0 + xr0; u0 = u0 > 0.f ? u0 : 0.2f * u0;
        float u1 = x1 + xr1; u1 = u1 > 0.f ? u1 : 0.2f * u1;
        float p0 = u0 * at0, p1 = u1 * at1;
#pragma unroll
        for (int m = 1; m <= 16; m <<= 1) { p0 += __shfl_xor(p0, m); p1 += __shfl_xor(p1, m); }
        p0 = __expf(p0); p1 = __expf(p1);
        num0 += p0 * x0; num1 += p1 * x1; den0 += p0; den1 += p1;
    }
    float gat0 = num0 / (den0 + 1e-16f), gat1 = num1 / (den1 + 1e-16f);

    // ---- TransformerConv (ball->ball) ----
    float q0 = toF(q[rowD + i0]), q1 = toF(q[rowD + i1]);
    float w0 = We[i0], w1 = We[i1];
    num0 = num1 = den0 = den1 = 0.f;
    beg = offsets[NB + d]; cnt = counts[NB + d];
    for (int j = 0; j < cnt; j++) {
        int e = pool[beg + j];
        int s = ep[e];
        float ea = ea_p[e];
        size_t rs = (size_t)s * 128;
        float k0 = toF(k[rs + i0]) + ea * w0, k1 = toF(k[rs + i1]) + ea * w1;
        float p0 = q0 * k0, p1 = q1 * k1;
#pragma unroll
        for (int m = 1; m <= 16; m <<= 1) { p0 += __shfl_xor(p0, m); p1 += __shfl_xor(p1, m); }
        p0 = __expf(p0 * 0.17677669529663687f);
        p1 = __expf(p1 * 0.17677669529663687f);
        float v0 = toF(v[rs + i0]) + ea * w0, v1 = toF(v[rs + i1]) + ea * w1;
        num0 += p0 * v0; num1 += p1 * v1; den0 += p0; den1 += p1;
    }
    float tr0 = num0 / (den0 + 1e-16f), tr1 = num1 / (den1 + 1e-16f);

    // ---- sum + LayerNorm ----
    float val0 = toF(skip[rowD + i0]) + gat0 + tr0 + x_ball[rowD + i0] + g_b[i0];
    float val1 = toF(skip[rowD + i1]) + gat1 + tr1 + x_ball[rowD + i1] + g_b[i1];
    float s = val0 + val1;
#pragma unroll
    for (int m = 1; m <= 32; m <<= 1) s += __shfl_xor(s, m);
    float mu = s * (1.f / 128.f);
    float d0 = val0 - mu, d1 = val1 - mu;
    float qv = d0 * d0 + d1 * d1;
#pragma unroll
    for (int m = 1; m <= 32; m <<= 1) qv += __shfl_xor(qv, m);
    float inv = rsqrtf(qv * (1.f / 128.f) + 1e-5f);
    out[rowD + i0] = d0 * inv * ln_g[i0] + ln_b[i0];
    out[rowD + i1] = d1 * inv * ln_g[i1] + ln_b[i1];
}

// ---------------- SAGE gather + mean: one wave per context node ----------------
__global__ void sage_gather_kernel(const float* __restrict__ x_ball, const int* __restrict__ ei,
                                   const int* __restrict__ offsets, const int* __restrict__ counts,
                                   const int* __restrict__ pool, float* __restrict__ summ) {
    int gid = blockIdx.x * 256 + threadIdx.x;
    int c = gid >> 6, l = gid & 63;
    if (c >= NC) return;
    int beg = offsets[2 * NB + c], cnt = counts[2 * NB + c];
    float s0 = 0.f, s1 = 0.f;
    for (int j = 0; j < cnt; j++) {
        int e = pool[beg + j];
        int s = ei[e];
        size_t rs = (size_t)s * 128;
        s0 += x_ball[rs + l];
        s1 += x_ball[rs + l + 64];
    }
    float m = fmaxf((float)cnt, 1.f);
    size_t rowC = (size_t)c * 128;
    summ[rowC + l] = s0 / m;
    summ[rowC + l + 64] = s1 / m;
}

// ---------------- LayerNorm ctx ----------------
__global__ void ln_ctx_kernel(const float* __restrict__ cb, const float* __restrict__ x,
                              const float* __restrict__ g, const float* __restrict__ b,
                              float* __restrict__ out) {
    int gid = blockIdx.x * 256 + threadIdx.x;
    int row = gid >> 6, lane = gid & 63;
    if (row >= NC) return;
    size_t i0 = (size_t)row * 128 + lane, i1 = i0 + 64;
    float v0 = cb[i0] + x[i0];
    float v1 = cb[i1] + x[i1];
    float s = v0 + v1;
#pragma unroll
    for (int m = 1; m <= 32; m <<= 1) s += __shfl_xor(s, m);
    float mu = s * (1.f / 128.f);
    float d0 = v0 - mu, d1 = v1 - mu;
    float qv = d0 * d0 + d1 * d1;
#pragma unroll
    for (int m = 1; m <= 32; m <<= 1) qv += __shfl_xor(qv, m);
    float inv = rsqrtf(qv * (1.f / 128.f) + 1e-5f);
    out[i0] = d0 * inv * g[lane] + b[lane];
    out[i1] = d1 * inv * g[lane + 64] + b[lane + 64];
}

__global__ void copy_player_kernel(const float* __restrict__ xp, float* __restrict__ out) {
    int t = blockIdx.x * 256 + threadIdx.x;
    if (t >= NP * 128) return;
    out[t] = xp[t];
}

extern "C" void kernel_launch(void* const* d_in, const int* in_sizes, int n_in,
                              void* d_out, int out_size, void* d_ws, size_t ws_size,
                              hipStream_t stream) {
    const float* x_ball = (const float*)d_in[0];
    const float* x_player = (const float*)d_in[1];
    const float* x_context = (const float*)d_in[2];
    const int* em = (const int*)d_in[3];
    const int* ep = (const int*)d_in[4];
    const int* ei = (const int*)d_in[5];
    const float* ea_p = (const float*)d_in[6];
    const float* g_Wl = (const float*)d_in[7];
    const float* g_Wr = (const float*)d_in[8];
    const float* g_att = (const float*)d_in[9];
    const float* g_b = (const float*)d_in[10];
    const float* t_Wq = (const float*)d_in[11];
    const float* t_bq = (const float*)d_in[12];
    const float* t_Wk = (const float*)d_in[13];
    const float* t_bk = (const float*)d_in[14];
    const float* t_Wv = (const float*)d_in[15];
    const float* t_bv = (const float*)d_in[16];
    const float* t_We = (const float*)d_in[17];
    const float* t_Wskip = (const float*)d_in[18];
    const float* t_bskip = (const float*)d_in[19];
    const float* s_Wl = (const float*)d_in[20];
    const float* s_bl = (const float*)d_in[21];
    const float* s_Wr = (const float*)d_in[22];
    const float* ln_ball_g = (const float*)d_in[23];
    const float* ln_ball_b = (const float*)d_in[24];
    const float* ln_ctx_g = (const float*)d_in[25];
    const float* ln_ctx_b = (const float*)d_in[26];
    float* out = (float*)d_out;

    // ---- workspace (~85 MB) ----
    float* ws = (float*)d_ws;
    size_t o = 0;
    float* summ = ws + o; o += (size_t)NC * 128;
    float* ctxb = ws + o; o += (size_t)NC * 128;
    int* ibase = (int*)(ws + o);
    int* counts = ibase;
    int* offsets = ibase + SEG_TOT;
    int* cursors = ibase + 2 * SEG_TOT;
    int* partials = ibase + 3 * SEG_TOT;          // 128 ints
    int* pool = ibase + 3 * SEG_TOT + 128;        // EM+EP+EI = 600000
    bf16* bws = (bf16*)(pool + EM_N + EP_N + EI_N);
    size_t ob = 0;
    bf16* xl = bws + ob;    ob += (size_t)NP * 128;
    bf16* xrB = bws + ob;   ob += (size_t)NB * 128;
    bf16* qB = bws + ob;    ob += (size_t)NB * 128;
    bf16* kB = bws + ob;    ob += (size_t)NB * 128;
    bf16* vB = bws + ob;    ob += (size_t)NB * 128;
    bf16* skipB = bws + ob; ob += (size_t)NB * 128;

    dim3 blk(256);
    // ---- CSR build ----
    hipMemsetAsync(counts, 0, SEG_TOT * sizeof(int), stream);
    hist_kernel<<<(EM_N + 255) / 256, blk, 0, stream>>>(em + EM_N, EM_N, 0, counts);
    hist_kernel<<<(EP_N + 255) / 256, blk, 0, stream>>>(ep + EP_N, EP_N, NB, counts);
    hist_kernel<<<(EI_N + 255) / 256, blk, 0, stream>>>(ei + EI_N, EI_N, 2 * NB, counts);
    scan1_kernel<<<NPART, blk, 0, stream>>>(counts, offsets, partials);
    scan2_kernel<<<1, blk, 0, stream>>>(partials);
    scan3_kernel<<<(SEG_TOT + 255) / 256, blk, 0, stream>>>(offsets, partials, cursors);
    fill_kernel<<<(EM_N + 255) / 256, blk, 0, stream>>>(em + EM_N, EM_N, 0, cursors, pool);
    fill_kernel<<<(EP_N + 255) / 256, blk, 0, stream>>>(ep + EP_N, EP_N, NB, cursors, pool);
    fill_kernel<<<(EI_N + 255) / 256, blk, 0, stream>>>(ei + EI_N, EI_N, 2 * NB, cursors, pool);

    // ---- dense projections ----
    gemm128_kernel<float, bf16, false, false><<<(NP + 15) / 16, blk, 0, stream>>>(x_player, g_Wl, nullptr, xl, NP);
    gemm128x5_kernel<<<(NB + 15) / 16, blk, 0, stream>>>(x_ball, g_Wr, t_Wq, t_Wk, t_Wv, t_Wskip,
                                                         t_bq, t_bk, t_bv, t_bskip,
                                                         xrB, qB, kB, vB, skipB, NB);

    // ---- fused ball pipeline (GAT + TR + skip + residual + LN) ----
    ball_fused_kernel<<<(NB * 64 + 255) / 256, blk, 0, stream>>>(
        xl, xrB, qB, kB, vB, skipB, x_ball, g_att, g_b, ea_p, t_We,
        em, ep, offsets, counts, pool, ln_ball_g, ln_ball_b, out);

    // ---- SAGE -> ctx ----
    sage_gather_kernel<<<(NC * 64 + 255) / 256, blk, 0, stream>>>(x_ball, ei, offsets, counts, pool, summ);
    gemm128_kernel<float, float, false, false><<<(NC + 15) / 16, blk, 0, stream>>>(x_context, s_Wr, nullptr, ctxb, NC);
    gemm128_kernel<float, float, true, true><<<(NC + 15) / 16, blk, 0, stream>>>(summ, s_Wl, s_bl, ctxb, NC);
    ln_ctx_kernel<<<(NC * 64 + 255) / 256, blk, 0, stream>>>(ctxb, x_context, ln_ctx_g, ln_ctx_b,
                                                             out + (size_t)NB * 128);
    copy_player_kernel<<<(NP * 128 + 255) / 256, blk, 0, stream>>>(x_player,
                                                                   out + (size_t)(NB + NC) * 128);
}

// Round 5
// 424.641 us; speedup vs baseline: 1.7353x; 1.2957x over previous
//
#include <hip/hip_runtime.h>
#include <hip/hip_bf16.h>

#define NB 60000
#define NP 2000
#define NC 4000
#define EM_N 150000
#define EP_N 300000
#define EI_N 150000
#define SEG_TOT (NB + NB + NC)                        // 124000 segment counters
#define SCAN_BLK 1024
#define NPART ((SEG_TOT + SCAN_BLK - 1) / SCAN_BLK)   // 122

typedef __hip_bfloat16 bf16;
typedef __attribute__((ext_vector_type(8))) short s8v;   // 8 bf16 raw bits (4 VGPRs)
typedef __attribute__((ext_vector_type(4))) float f4v;

__device__ __forceinline__ float toF(float x) { return x; }
__device__ __forceinline__ float toF(bf16 x) { return __bfloat162float(x); }
__device__ __forceinline__ void stC(float* C, size_t idx, float v) { C[idx] = v; }
__device__ __forceinline__ void stC(bf16* C, size_t idx, float v) { C[idx] = __float2bfloat16(v); }
__device__ __forceinline__ short f2bs(float f) {
    bf16 h = __float2bfloat16(f);
    return __builtin_bit_cast(short, h);
}

// ---------------- generic VALU GEMM (small M): C[M,128] = A[M,128] @ W[128,128] (+bias)(+=C) ----------------
template<typename AT, typename CT, bool ACC, bool BIAS>
__global__ void gemm128_kernel(const AT* __restrict__ A, const float* __restrict__ W,
                               const float* __restrict__ bias, CT* __restrict__ C, int M) {
    __shared__ float Al[16 * 128];
    const int tid = threadIdx.x;
    const int row0 = blockIdx.x * 16;
    for (int i = tid; i < 16 * 128; i += 256) {
        int r = row0 + (i >> 7);
        Al[i] = (r < M) ? toF(A[(size_t)r * 128 + (i & 127)]) : 0.f;
    }
    __syncthreads();
    const int col = tid & 127, rg = tid >> 7;
    float acc[8];
#pragma unroll
    for (int i = 0; i < 8; i++) acc[i] = 0.f;
    for (int k = 0; k < 128; k++) {
        float w = W[k * 128 + col];
#pragma unroll
        for (int i = 0; i < 8; i++) acc[i] += Al[(rg * 8 + i) * 128 + k] * w;
    }
    float bv = 0.f;
    if constexpr (BIAS) bv = bias[col];
#pragma unroll
    for (int i = 0; i < 8; i++) {
        int r = row0 + rg * 8 + i;
        if (r < M) {
            size_t idx = (size_t)r * 128 + col;
            float o = acc[i] + bv;
            if constexpr (ACC) o += toF(C[idx]);
            stC(C, idx, o);
        }
    }
}

// ---------------- weight prep: Wt[w][n][k] = W_w[k][n] as bf16 bits ----------------
__global__ void wt_prep_kernel(const float* __restrict__ W0, const float* __restrict__ W1,
                               const float* __restrict__ W2, const float* __restrict__ W3,
                               const float* __restrict__ W4, ushort* __restrict__ Wt) {
    int t = blockIdx.x * 256 + threadIdx.x;
    if (t >= 5 * 16384) return;
    int w = t >> 14, r = t & 16383, k = r >> 7, n = r & 127;
    const float* W = (w == 0) ? W0 : (w == 1) ? W1 : (w == 2) ? W2 : (w == 3) ? W3 : W4;
    Wt[w * 16384 + n * 128 + k] = (ushort)f2bs(W[k * 128 + n]);  // coalesced read, scattered 2B write
}

// ---------------- MFMA fused 5-matrix GEMM on x_ball ----------------
// Outputs: xr[NB,128], q[NB,128], kv[NB,256] (k|v interleaved), skip[NB,128], all bf16.
__global__ __launch_bounds__(256) void gemm5_mfma_kernel(
    const float* __restrict__ A, const ushort* __restrict__ Wt,
    const float* __restrict__ bq, const float* __restrict__ bk,
    const float* __restrict__ bv_, const float* __restrict__ bskip,
    bf16* __restrict__ xrB, bf16* __restrict__ qB, bf16* __restrict__ kvB,
    bf16* __restrict__ skipB) {
    const int lane = threadIdx.x & 63;
    const int wv = threadIdx.x >> 6;
    const int quad = lane >> 4, l16 = lane & 15;
    const int mbase = blockIdx.x * 128 + wv * 32;

    // ---- A-fragments: 2 m-tiles x 4 k-tiles, A[m=l16][k=kt*32+quad*8+j] ----
    s8v a[2][4];
#pragma unroll
    for (int mt = 0; mt < 2; mt++) {
        int row = mbase + mt * 16 + l16;
        if (row >= NB) row = NB - 1;  // clamp (stores predicated)
        const float* ap = A + (size_t)row * 128 + quad * 8;
#pragma unroll
        for (int kt = 0; kt < 4; kt++) {
            const float4* p = (const float4*)(ap + kt * 32);
            float4 u = p[0], v = p[1];
            s8v f;
            f[0] = f2bs(u.x); f[1] = f2bs(u.y); f[2] = f2bs(u.z); f[3] = f2bs(u.w);
            f[4] = f2bs(v.x); f[5] = f2bs(v.y); f[6] = f2bs(v.z); f[7] = f2bs(v.w);
            a[mt][kt] = f;
        }
    }

#pragma unroll
    for (int w = 0; w < 5; w++) {
        const ushort* wt = Wt + w * 16384;
        bf16* op; const float* bp; int stride;
        if (w == 0)      { op = xrB;      bp = nullptr; stride = 128; }
        else if (w == 1) { op = qB;       bp = bq;     stride = 128; }
        else if (w == 2) { op = kvB;      bp = bk;     stride = 256; }
        else if (w == 3) { op = kvB + 128; bp = bv_;   stride = 256; }
        else             { op = skipB;    bp = bskip;  stride = 128; }
#pragma unroll
        for (int nt = 0; nt < 8; nt++) {
            int col = nt * 16 + l16;
            // B-fragments: lane holds B[k=kt*32+quad*8+j][n=col] = Wt[col][k...k+7]
            s8v b[4];
#pragma unroll
            for (int kt = 0; kt < 4; kt++)
                b[kt] = *(const s8v*)(wt + col * 128 + kt * 32 + quad * 8);
            float bval = bp ? bp[col] : 0.f;
#pragma unroll
            for (int mt = 0; mt < 2; mt++) {
                f4v acc = {0.f, 0.f, 0.f, 0.f};
#pragma unroll
                for (int kt = 0; kt < 4; kt++)
                    acc = __builtin_amdgcn_mfma_f32_16x16x32_bf16(a[mt][kt], b[kt], acc, 0, 0, 0);
#pragma unroll
                for (int r = 0; r < 4; r++) {
                    int row = mbase + mt * 16 + quad * 4 + r;
                    if (row < NB)
                        op[(size_t)row * stride + col] = __float2bfloat16(acc[r] + bval);
                }
            }
        }
    }
}

// ---------------- CSR build ----------------
__global__ void hist_kernel(const int* __restrict__ dst, int n, int segBase, int* __restrict__ counts) {
    int t = blockIdx.x * 256 + threadIdx.x;
    if (t >= n) return;
    atomicAdd(&counts[segBase + dst[t]], 1);
}

__global__ void scan1_kernel(const int* __restrict__ counts, int* __restrict__ offsets,
                             int* __restrict__ partials) {
    __shared__ int sd[256];
    int b = blockIdx.x, tid = threadIdx.x;
    int base = b * SCAN_BLK + tid * 4;
    int v[4]; int ts = 0;
#pragma unroll
    for (int j = 0; j < 4; j++) { int idx = base + j; v[j] = (idx < SEG_TOT) ? counts[idx] : 0; ts += v[j]; }
    sd[tid] = ts;
    for (int off = 1; off < 256; off <<= 1) {
        __syncthreads(); int t = (tid >= off) ? sd[tid - off] : 0;
        __syncthreads(); sd[tid] += t;
    }
    int run = sd[tid] - ts;
#pragma unroll
    for (int j = 0; j < 4; j++) { int idx = base + j; if (idx < SEG_TOT) offsets[idx] = run; run += v[j]; }
    if (tid == 255) partials[b] = sd[255];
}

__global__ void scan2_kernel(int* __restrict__ partials) {
    __shared__ int sd[256];
    int tid = threadIdx.x;
    int v = (tid < NPART) ? partials[tid] : 0;
    sd[tid] = v;
    for (int off = 1; off < 256; off <<= 1) {
        __syncthreads(); int t = (tid >= off) ? sd[tid - off] : 0;
        __syncthreads(); sd[tid] += t;
    }
    if (tid < NPART) partials[tid] = sd[tid] - v;
}

__global__ void scan3_kernel(int* __restrict__ offsets, const int* __restrict__ partials,
                             int* __restrict__ cursors) {
    int t = blockIdx.x * 256 + threadIdx.x;
    if (t >= SEG_TOT) return;
    int o = offsets[t] + partials[t >> 10];
    offsets[t] = o;
    cursors[t] = o;
}

// fill: store RESOLVED source id (+ optional edge attr) — removes an indirection in the gather
__global__ void fill_kernel(const int* __restrict__ dst, const int* __restrict__ src,
                            const float* __restrict__ eattr, int n, int segBase,
                            int* __restrict__ cursors, int* __restrict__ pool,
                            float* __restrict__ pool_ea) {
    int t = blockIdx.x * 256 + threadIdx.x;
    if (t >= n) return;
    int pos = atomicAdd(&cursors[segBase + dst[t]], 1);
    pool[pos] = src[t];
    if (eattr) pool_ea[pos] = eattr[t];
}

// ---------------- fused ball kernel: GAT + TR + skip + residual + LN ----------------
__global__ void ball_fused_kernel(
    const bf16* __restrict__ xl, const bf16* __restrict__ xr, const bf16* __restrict__ q,
    const bf16* __restrict__ kv, const bf16* __restrict__ skip,
    const float* __restrict__ x_ball, const float* __restrict__ g_att, const float* __restrict__ g_b,
    const float* __restrict__ We,
    const int* __restrict__ offsets, const int* __restrict__ counts,
    const int* __restrict__ pool, const float* __restrict__ pool_ea,
    const float* __restrict__ ln_g, const float* __restrict__ ln_b, float* __restrict__ out) {
    int gid = blockIdx.x * 256 + threadIdx.x;
    int d = gid >> 6, l = gid & 63;
    if (d >= NB) return;
    int i0 = l, i1 = l + 64;
    size_t rowD = (size_t)d * 128;

    // ---- GATv2 (player->ball) ----
    float xr0 = toF(xr[rowD + i0]), xr1 = toF(xr[rowD + i1]);
    float at0 = g_att[i0], at1 = g_att[i1];
    float num0 = 0.f, num1 = 0.f, den0 = 0.f, den1 = 0.f;
    int beg = offsets[d], cnt = counts[d];
    for (int j = 0; j < cnt; j++) {
        int s = pool[beg + j];
        size_t rs = (size_t)s * 128;
        float x0 = toF(xl[rs + i0]), x1 = toF(xl[rs + i1]);
        float u0 = x0 + xr0; u0 = u0 > 0.f ? u0 : 0.2f * u0;
        float u1 = x1 + xr1; u1 = u1 > 0.f ? u1 : 0.2f * u1;
        float p0 = u0 * at0, p1 = u1 * at1;
#pragma unroll
        for (int m = 1; m <= 16; m <<= 1) { p0 += __shfl_xor(p0, m); p1 += __shfl_xor(p1, m); }
        p0 = __expf(p0); p1 = __expf(p1);
        num0 += p0 * x0; num1 += p1 * x1; den0 += p0; den1 += p1;
    }
    float gat0 = num0 / (den0 + 1e-16f), gat1 = num1 / (den1 + 1e-16f);

    // ---- TransformerConv (ball->ball), kv interleaved ----
    float q0 = toF(q[rowD + i0]), q1 = toF(q[rowD + i1]);
    float w0 = We[i0], w1 = We[i1];
    num0 = num1 = den0 = den1 = 0.f;
    beg = offsets[NB + d]; cnt = counts[NB + d];
    for (int j = 0; j < cnt; j++) {
        int s = pool[beg + j];
        float ea = pool_ea[beg + j];
        size_t rs = (size_t)s * 256;
        float k0 = toF(kv[rs + i0]) + ea * w0, k1 = toF(kv[rs + i1]) + ea * w1;
        float p0 = q0 * k0, p1 = q1 * k1;
#pragma unroll
        for (int m = 1; m <= 16; m <<= 1) { p0 += __shfl_xor(p0, m); p1 += __shfl_xor(p1, m); }
        p0 = __expf(p0 * 0.17677669529663687f);
        p1 = __expf(p1 * 0.17677669529663687f);
        float v0 = toF(kv[rs + 128 + i0]) + ea * w0, v1 = toF(kv[rs + 128 + i1]) + ea * w1;
        num0 += p0 * v0; num1 += p1 * v1; den0 += p0; den1 += p1;
    }
    float tr0 = num0 / (den0 + 1e-16f), tr1 = num1 / (den1 + 1e-16f);

    // ---- sum + LayerNorm ----
    float val0 = toF(skip[rowD + i0]) + gat0 + tr0 + x_ball[rowD + i0] + g_b[i0];
    float val1 = toF(skip[rowD + i1]) + gat1 + tr1 + x_ball[rowD + i1] + g_b[i1];
    float s = val0 + val1;
#pragma unroll
    for (int m = 1; m <= 32; m <<= 1) s += __shfl_xor(s, m);
    float mu = s * (1.f / 128.f);
    float d0 = val0 - mu, d1 = val1 - mu;
    float qv = d0 * d0 + d1 * d1;
#pragma unroll
    for (int m = 1; m <= 32; m <<= 1) qv += __shfl_xor(qv, m);
    float inv = rsqrtf(qv * (1.f / 128.f) + 1e-5f);
    out[rowD + i0] = d0 * inv * ln_g[i0] + ln_b[i0];
    out[rowD + i1] = d1 * inv * ln_g[i1] + ln_b[i1];
}

// ---------------- SAGE gather + mean ----------------
__global__ void sage_gather_kernel(const float* __restrict__ x_ball,
                                   const int* __restrict__ offsets, const int* __restrict__ counts,
                                   const int* __restrict__ pool, float* __restrict__ summ) {
    int gid = blockIdx.x * 256 + threadIdx.x;
    int c = gid >> 6, l = gid & 63;
    if (c >= NC) return;
    int beg = offsets[2 * NB + c], cnt = counts[2 * NB + c];
    float s0 = 0.f, s1 = 0.f;
    for (int j = 0; j < cnt; j++) {
        int s = pool[beg + j];
        size_t rs = (size_t)s * 128;
        s0 += x_ball[rs + l];
        s1 += x_ball[rs + l + 64];
    }
    float m = fmaxf((float)cnt, 1.f);
    size_t rowC = (size_t)c * 128;
    summ[rowC + l] = s0 / m;
    summ[rowC + l + 64] = s1 / m;
}

// ---------------- LayerNorm ctx ----------------
__global__ void ln_ctx_kernel(const float* __restrict__ cb, const float* __restrict__ x,
                              const float* __restrict__ g, const float* __restrict__ b,
                              float* __restrict__ out) {
    int gid = blockIdx.x * 256 + threadIdx.x;
    int row = gid >> 6, lane = gid & 63;
    if (row >= NC) return;
    size_t i0 = (size_t)row * 128 + lane, i1 = i0 + 64;
    float v0 = cb[i0] + x[i0];
    float v1 = cb[i1] + x[i1];
    float s = v0 + v1;
#pragma unroll
    for (int m = 1; m <= 32; m <<= 1) s += __shfl_xor(s, m);
    float mu = s * (1.f / 128.f);
    float d0 = v0 - mu, d1 = v1 - mu;
    float qv = d0 * d0 + d1 * d1;
#pragma unroll
    for (int m = 1; m <= 32; m <<= 1) qv += __shfl_xor(qv, m);
    float inv = rsqrtf(qv * (1.f / 128.f) + 1e-5f);
    out[i0] = d0 * inv * g[lane] + b[lane];
    out[i1] = d1 * inv * g[lane + 64] + b[lane + 64];
}

__global__ void copy_player_kernel(const float* __restrict__ xp, float* __restrict__ out) {
    int t = blockIdx.x * 256 + threadIdx.x;
    if (t >= NP * 128) return;
    out[t] = xp[t];
}

extern "C" void kernel_launch(void* const* d_in, const int* in_sizes, int n_in,
                              void* d_out, int out_size, void* d_ws, size_t ws_size,
                              hipStream_t stream) {
    const float* x_ball = (const float*)d_in[0];
    const float* x_player = (const float*)d_in[1];
    const float* x_context = (const float*)d_in[2];
    const int* em = (const int*)d_in[3];
    const int* ep = (const int*)d_in[4];
    const int* ei = (const int*)d_in[5];
    const float* ea_p = (const float*)d_in[6];
    const float* g_Wl = (const float*)d_in[7];
    const float* g_Wr = (const float*)d_in[8];
    const float* g_att = (const float*)d_in[9];
    const float* g_b = (const float*)d_in[10];
    const float* t_Wq = (const float*)d_in[11];
    const float* t_bq = (const float*)d_in[12];
    const float* t_Wk = (const float*)d_in[13];
    const float* t_bk = (const float*)d_in[14];
    const float* t_Wv = (const float*)d_in[15];
    const float* t_bv = (const float*)d_in[16];
    const float* t_We = (const float*)d_in[17];
    const float* t_Wskip = (const float*)d_in[18];
    const float* t_bskip = (const float*)d_in[19];
    const float* s_Wl = (const float*)d_in[20];
    const float* s_bl = (const float*)d_in[21];
    const float* s_Wr = (const float*)d_in[22];
    const float* ln_ball_g = (const float*)d_in[23];
    const float* ln_ball_b = (const float*)d_in[24];
    const float* ln_ctx_g = (const float*)d_in[25];
    const float* ln_ctx_b = (const float*)d_in[26];
    float* out = (float*)d_out;

    // ---- workspace (~88 MB) ----
    float* ws = (float*)d_ws;
    size_t o = 0;
    float* summ = ws + o;    o += (size_t)NC * 128;
    float* ctxb = ws + o;    o += (size_t)NC * 128;
    float* pool_ea = ws + o; o += (size_t)(EM_N + EP_N + EI_N);
    int* counts = (int*)(ws + o);   o += SEG_TOT;
    int* offsets = (int*)(ws + o);  o += SEG_TOT;
    int* cursors = (int*)(ws + o);  o += SEG_TOT;
    int* partials = (int*)(ws + o); o += 128;
    int* pool = (int*)(ws + o);     o += (size_t)(EM_N + EP_N + EI_N);
    ushort* Wt = (ushort*)(ws + o); o += (5 * 16384) / 2;   // 160KB bf16 bits, 16B-aligned
    bf16* bws = (bf16*)(ws + o);
    size_t ob = 0;
    bf16* xl = bws + ob;    ob += (size_t)NP * 128;
    bf16* xrB = bws + ob;   ob += (size_t)NB * 128;
    bf16* qB = bws + ob;    ob += (size_t)NB * 128;
    bf16* kvB = bws + ob;   ob += (size_t)NB * 256;   // k|v interleaved per node
    bf16* skipB = bws + ob; ob += (size_t)NB * 128;

    dim3 blk(256);
    // ---- CSR build ----
    hipMemsetAsync(counts, 0, SEG_TOT * sizeof(int), stream);
    hist_kernel<<<(EM_N + 255) / 256, blk, 0, stream>>>(em + EM_N, EM_N, 0, counts);
    hist_kernel<<<(EP_N + 255) / 256, blk, 0, stream>>>(ep + EP_N, EP_N, NB, counts);
    hist_kernel<<<(EI_N + 255) / 256, blk, 0, stream>>>(ei + EI_N, EI_N, 2 * NB, counts);
    scan1_kernel<<<NPART, blk, 0, stream>>>(counts, offsets, partials);
    scan2_kernel<<<1, blk, 0, stream>>>(partials);
    scan3_kernel<<<(SEG_TOT + 255) / 256, blk, 0, stream>>>(offsets, partials, cursors);
    fill_kernel<<<(EM_N + 255) / 256, blk, 0, stream>>>(em + EM_N, em, nullptr, EM_N, 0, cursors, pool, pool_ea);
    fill_kernel<<<(EP_N + 255) / 256, blk, 0, stream>>>(ep + EP_N, ep, ea_p, EP_N, NB, cursors, pool, pool_ea);
    fill_kernel<<<(EI_N + 255) / 256, blk, 0, stream>>>(ei + EI_N, ei, nullptr, EI_N, 2 * NB, cursors, pool, pool_ea);

    // ---- dense projections ----
    wt_prep_kernel<<<(5 * 16384 + 255) / 256, blk, 0, stream>>>(g_Wr, t_Wq, t_Wk, t_Wv, t_Wskip, Wt);
    gemm128_kernel<float, bf16, false, false><<<(NP + 15) / 16, blk, 0, stream>>>(x_player, g_Wl, nullptr, xl, NP);
    gemm5_mfma_kernel<<<(NB + 127) / 128, blk, 0, stream>>>(x_ball, Wt, t_bq, t_bk, t_bv, t_bskip,
                                                            xrB, qB, kvB, skipB);

    // ---- fused ball pipeline ----
    ball_fused_kernel<<<(NB * 64 + 255) / 256, blk, 0, stream>>>(
        xl, xrB, qB, kvB, skipB, x_ball, g_att, g_b, t_We,
        offsets, counts, pool, pool_ea, ln_ball_g, ln_ball_b, out);

    // ---- SAGE -> ctx ----
    sage_gather_kernel<<<(NC * 64 + 255) / 256, blk, 0, stream>>>(x_ball, offsets, counts, pool, summ);
    gemm128_kernel<float, float, false, false><<<(NC + 15) / 16, blk, 0, stream>>>(x_context, s_Wr, nullptr, ctxb, NC);
    gemm128_kernel<float, float, true, true><<<(NC + 15) / 16, blk, 0, stream>>>(summ, s_Wl, s_bl, ctxb, NC);
    ln_ctx_kernel<<<(NC * 64 + 255) / 256, blk, 0, stream>>>(ctxb, x_context, ln_ctx_g, ln_ctx_b,
                                                             out + (size_t)NB * 128);
    copy_player_kernel<<<(NP * 128 + 255) / 256, blk, 0, stream>>>(x_player,
                                                                   out + (size_t)(NB + NC) * 128);
}